// Round 1
// baseline (303.059 us; speedup 1.0000x reference)
//
#include <hip/hip_runtime.h>

// out[i] = probs[X[i,0]*125000 + X[i,1]*2500 + X[i,2]*50 + X[i,3]]
// probs: 50^4 = 6,250,000 float32 (25 MB) — fits L3; per-XCD L2 (4 MB) holds ~16%.
// X: [N,4] int32 — 16 B/sample, streamed exactly once.
//
// v2 changes vs v1 (one-sample-per-thread):
//  - 4 samples/thread: 4 independent X loads then 4 independent gathers in
//    flight per thread (4x memory-level parallelism for the latency-bound
//    dependent-gather chain), one float4 store (4x fewer write requests).
//  - nontemporal hints on the X stream and out stream so they do not evict
//    probs-table lines from L2 (gather hit rate is the traffic lever).
//  - gather loads stay cached (we WANT probs in L2/L3).

typedef int   iv4 __attribute__((ext_vector_type(4)));
typedef float fv4 __attribute__((ext_vector_type(4)));

__global__ __launch_bounds__(256) void jc_gather_k4(
    const iv4* __restrict__ X,
    const float* __restrict__ probs,
    float* __restrict__ out,
    int n)  // n = number of samples
{
    int t = blockIdx.x * blockDim.x + threadIdx.x;
    int base = t << 2;  // 4 samples per thread

    if (base + 3 < n) {
        // 4 independent 16B streaming loads (nt: bypass/deprioritize L2)
        iv4 x0 = __builtin_nontemporal_load(&X[base + 0]);
        iv4 x1 = __builtin_nontemporal_load(&X[base + 1]);
        iv4 x2 = __builtin_nontemporal_load(&X[base + 2]);
        iv4 x3 = __builtin_nontemporal_load(&X[base + 3]);

        int i0 = ((x0.x * 50 + x0.y) * 50 + x0.z) * 50 + x0.w;
        int i1 = ((x1.x * 50 + x1.y) * 50 + x1.z) * 50 + x1.w;
        int i2 = ((x2.x * 50 + x2.y) * 50 + x2.z) * 50 + x2.w;
        int i3 = ((x3.x * 50 + x3.y) * 50 + x3.z) * 50 + x3.w;

        // 4 independent random gathers in flight (cached: table reuse is the win)
        fv4 r;
        r.x = probs[i0];
        r.y = probs[i1];
        r.z = probs[i2];
        r.w = probs[i3];

        // single 16B streaming store
        __builtin_nontemporal_store(r, (fv4*)(out + base));
    } else if (base < n) {
        // tail (n % 4 != 0) — scalar
        for (int k = base; k < n; ++k) {
            iv4 x = X[k];
            int idx = ((x.x * 50 + x.y) * 50 + x.z) * 50 + x.w;
            out[k] = probs[idx];
        }
    }
}

extern "C" void kernel_launch(void* const* d_in, const int* in_sizes, int n_in,
                              void* d_out, int out_size, void* d_ws, size_t ws_size,
                              hipStream_t stream) {
    const float* probs = (const float*)d_in[0];
    const iv4*   X     = (const iv4*)d_in[1];   // in_sizes[1] = N*4 int32
    float* out = (float*)d_out;

    int n = out_size;            // 8,000,000 samples
    int threads = (n + 3) >> 2;  // 4 samples per thread
    int block = 256;
    int grid = (threads + block - 1) / block;
    jc_gather_k4<<<grid, block, 0, stream>>>(X, probs, out, n);
}